// Round 11
// baseline (126.529 us; speedup 1.0000x reference)
//
#include <hip/hip_runtime.h>
#include <stdint.h>

#define NPTS   8192
#define NROWS  (NPTS * 16)
#define SLOPE  0.01f
#define BN_EPS 1e-5f

// binned-KNN parameters (points binned; queries NOT binned -- one wave per query)
#define TP     0.13f     // tier-0 pool radius: interior lambda=75
#define TP2    (TP * TP)
#define CAP    152       // tier-0 cap (+8.8 sigma); fail -> tier-1
#define TF     0.2f      // tier-1 radius (corner-safe: d16 <= ~0.155, proven R6-R9)
#define TF2    0.04f
#define CAPF   408       // tier-1 cap; fail -> exact full scan
#define EPSB   1e-5f     // conservative cell-range slop (>> fp rounding)

// ---- workspace layout (bytes) ----
#define OFF_Q      0u          // 8192x128 f32
#define OFF_KP     4194304u    // 8192x128 f32
#define OFF_VP     8388608u    // 8192x128 f32
#define OFF_STATS  12582912u   // st1[16*256] st2[16*256] bn1[256] bn2[256]
#define OFF_TAB    12845056u   // ints: pcnt[512] poff[513] pcur[512]
#define OFF_IDX    13041664u   // 131072 i32 (8192 x 16 neighbor ids)
#define OFF_BIG    13585408u   // bp[8256]f4 (dead after knn), later aliased by Y bf16 (33.5MB)
#define WS_NEED    47139840u

// TAB int offsets
#define T_PCNT 0
#define T_POFF 512
#define T_PCUR 1025

typedef __bf16 bf16x8 __attribute__((ext_vector_type(8)));
typedef float  f32x4  __attribute__((ext_vector_type(4)));

__device__ __forceinline__ unsigned int pack_bf2(float lo, float hi) {
  unsigned int a = __float_as_uint(lo);
  unsigned int b = __float_as_uint(hi);
  unsigned int ra = (a + 0x7fffu + ((a >> 16) & 1u)) >> 16;
  unsigned int rb = (b + 0x7fffu + ((b >> 16) & 1u)) & 0xffff0000u;
  return ra | rb;
}
__device__ __forceinline__ unsigned short bf1(float v) {
  unsigned int a = __float_as_uint(v);
  return (unsigned short)((a + 0x7fffu + ((a >> 16) & 1u)) >> 16);
}
__device__ __forceinline__ float bf2f(unsigned short u) {
  return __uint_as_float(((unsigned int)u) << 16);
}

__device__ __forceinline__ int cell_of(float x, float y, float z) {
  int cx = min(7, max(0, (int)(x * 8.f)));
  int cy = min(7, max(0, (int)(y * 8.f)));
  int cz = min(7, max(0, (int)(z * 8.f)));
  return (cz * 8 + cy) * 8 + cx;
}

__device__ __forceinline__ void insert16(unsigned long long* key, unsigned long long kk) {
  if (kk < key[15]) {
    #pragma unroll
    for (int u = 15; u >= 1; --u) {
      bool cm1 = kk < key[u - 1];
      bool cs  = kk < key[u];
      key[u] = cm1 ? key[u - 1] : (cs ? kk : key[u]);
    }
    key[0] = (kk < key[0]) ? kk : key[0];
  }
}

// top-16 in exact (dist, original-idx) lex order from an LDS pool of n keys.
// D = ceil(cap/64). Proven R8/R9 structure (f32-head butterfly + ballot/readlane).
template<int D>
__device__ __forceinline__ void extract_topk(const unsigned long long* __restrict__ poolq, int n, int lane,
                                             int* __restrict__ sidxq, int* __restrict__ idxoq) {
  unsigned long long lst[D];
  #pragma unroll
  for (int j = 0; j < D; ++j) lst[j] = ~0ull;
  for (int j = lane; j < n; j += 64) {
    unsigned long long kk = poolq[j];
    #pragma unroll
    for (int u = D - 1; u >= 1; --u) {
      bool cm1 = kk < lst[u - 1];
      bool cs  = kk < lst[u];
      lst[u] = cm1 ? lst[u - 1] : (cs ? kk : lst[u]);
    }
    lst[0] = (kk < lst[0]) ? kk : lst[0];
  }
  int myidx = 0;
  #pragma unroll 1
  for (int r = 0; r < 16; ++r) {
    const float hd = __uint_as_float((unsigned int)(lst[0] >> 32));  // empty -> NaN, loses
    float wm = hd;
    #pragma unroll
    for (int o = 32; o; o >>= 1) wm = fminf(wm, __shfl_xor(wm, o));
    bool iswin = (hd == wm);
    const unsigned long long wmask = __ballot(iswin);
    unsigned int widx;
    if (__popcll(wmask) > 1) {           // exact dist tie: lex tie-break by min idx
      unsigned int mi = iswin ? (unsigned int)lst[0] : 0xffffffffu;
      #pragma unroll
      for (int o = 32; o; o >>= 1) {
        unsigned int u = (unsigned int)__shfl_xor((int)mi, o);
        mi = (u < mi) ? u : mi;
      }
      widx = mi;
      iswin = iswin && ((unsigned int)lst[0] == mi);
    } else {
      const int wl = (int)__builtin_ctzll(wmask);
      widx = (unsigned int)__builtin_amdgcn_readlane((int)(unsigned int)lst[0], wl);
    }
    #pragma unroll
    for (int u = 0; u < D - 1; ++u) lst[u] = iswin ? lst[u + 1] : lst[u];
    lst[D - 1] = iswin ? ~0ull : lst[D - 1];
    if (lane == r) myidx = (int)widx;
  }
  if (lane < 16) { idxoq[lane] = myidx; sidxq[lane] = myidx; }
}

// scan all binned points within the axis box (q +- rad): append exact-dd < r2 candidates
// (original idx in key) to the wave-private pool via ballot+prefix-popc. Returns total count
// (counts past cap too -> caller detects overflow). bp has 64 sentinel pad rows (1e9 coords)
// so the chunk over-read is harmless by value; the pos<rer mask is kept as belt-and-braces.
__device__ __forceinline__ int scan_ball(const int* __restrict__ poff, const float4* __restrict__ bp,
                                         float qx, float qy, float qz, float rad, float r2, int cap,
                                         unsigned long long* __restrict__ poolw,
                                         int lane, unsigned long long below) {
  const int lx = max(0, (int)floorf((qx - rad - EPSB) * 8.f));
  const int hx = min(7, (int)floorf((qx + rad + EPSB) * 8.f));
  const int ly = max(0, (int)floorf((qy - rad - EPSB) * 8.f));
  const int hy = min(7, (int)floorf((qy + rad + EPSB) * 8.f));
  const int lz = max(0, (int)floorf((qz - rad - EPSB) * 8.f));
  const int hz = min(7, (int)floorf((qz + rad + EPSB) * 8.f));
  const int nrY = hy - ly + 1, nrows = nrY * (hz - lz + 1);   // <= 25 (rad<=0.2)
  int zi = 0;
  #pragma unroll
  for (int z2 = 1; z2 < 5; ++z2) zi += (lane >= z2 * nrY) ? 1 : 0;   // lane/nrY for lane < 5*nrY
  const int yi = lane - zi * nrY;
  int rs = 0, re = 0;
  if (lane < nrows) {
    const int crow = ((lz + zi) * 8 + (ly + yi)) * 8;
    rs = poff[crow + lx]; re = poff[crow + hx + 1];
  }
  int cnt = 0;
  for (int r = 0; r < nrows; ++r) {
    const int rsr = __builtin_amdgcn_readlane(rs, r);
    const int rer = __builtin_amdgcn_readlane(re, r);
    for (int base = rsr; base < rer; base += 64) {
      const int pos = base + lane;                // over-read hits sentinel pad (dd huge)
      const float4 pp = bp[pos];
      float dx = qx - pp.x, dy = qy - pp.y, dz = qz - pp.z;
      float dd = fmaf(dx, dx, fmaf(dy, dy, dz * dz));   // exact reference-ordering formula
      bool g = (pos < rer) && (dd < r2);
      unsigned long long mask = __ballot(g);
      int p2 = cnt + (int)__popcll(mask & below);
      if (g && p2 < cap)
        poolw[p2] = ((unsigned long long)__float_as_uint(dd) << 32) | (unsigned int)__float_as_int(pp.w);
      cnt += (int)__popcll(mask);
    }
  }
  return cnt;
}

// ---------------- zero counters/stats + write bp sentinel pad ----------------
__global__ __launch_bounds__(256) void k_zero(int* __restrict__ tab,
                                              float* __restrict__ stats,
                                              float4* __restrict__ bp) {
  const int T = blockIdx.x * 256 + threadIdx.x;   // 8448 threads
  if (T < 8192) stats[T] = 0.f;                   // st1[4096] + st2[4096]
  if (T < 512)  tab[T_PCNT + T] = 0;
  if (T < 64)   bp[NPTS + T] = make_float4(1e9f, 1e9f, 1e9f, __int_as_float(0));
}

// ---------------- binning: histogram (points only) ----------------
__global__ __launch_bounds__(256) void k_count(const float* __restrict__ xyz_i,
                                               int* __restrict__ tab) {
  const int t = blockIdx.x * 256 + threadIdx.x;   // 8192
  atomicAdd(&tab[T_PCNT + cell_of(xyz_i[t * 3], xyz_i[t * 3 + 1], xyz_i[t * 3 + 2])], 1);
}

// ---------------- binning: prefix sum ----------------
__global__ __launch_bounds__(512) void k_offsets(int* __restrict__ tab) {
  __shared__ int ls[512];
  const int t = threadIdx.x;
  const int v = tab[T_PCNT + t];
  ls[t] = v;
  __syncthreads();
  for (int ofs = 1; ofs < 512; ofs <<= 1) {
    int add = (t >= ofs) ? ls[t - ofs] : 0;
    __syncthreads();
    ls[t] += add;
    __syncthreads();
  }
  tab[T_POFF + t] = ls[t] - v;                    // exclusive prefix
  tab[T_PCUR + t] = ls[t] - v;
  if (t == 511) tab[T_POFF + 512] = ls[511];
}

// ---------------- binning: scatter points (original idx packed into .w) ----------------
__global__ __launch_bounds__(256) void k_scatter(const float* __restrict__ xyz_i,
                                                 int* __restrict__ tab,
                                                 float4* __restrict__ bp) {
  const int t = blockIdx.x * 256 + threadIdx.x;   // 8192
  float x = xyz_i[t * 3], y = xyz_i[t * 3 + 1], z = xyz_i[t * 3 + 2];
  int pos = atomicAdd(&tab[T_PCUR + cell_of(x, y, z)], 1);
  bp[pos] = make_float4(x, y, z, __int_as_float(t));
}

// ---------------- projections via MFMA (exact R9 version, proven) ----------------
__global__ __launch_bounds__(256) void k_proj(const float* __restrict__ fea_i,
                                              const float* __restrict__ fea_last,
                                              const float* __restrict__ Wq,
                                              const float* __restrict__ Wk,
                                              const float* __restrict__ Wv,
                                              const float* __restrict__ bq,
                                              const float* __restrict__ bk,
                                              const float* __restrict__ bv,
                                              float* __restrict__ Qo,
                                              float* __restrict__ Kpo,
                                              float* __restrict__ Vpo) {
  const int z = blockIdx.y;
  const float* A    = (z == 0) ? fea_last : fea_i;
  const float* W    = (z == 0) ? Wq : ((z == 1) ? Wk : Wv);
  const float* bias = (z == 0) ? bq : ((z == 1) ? bk : bv);
  float* Out        = (z == 0) ? Qo : ((z == 1) ? Kpo : Vpo);

  __shared__ unsigned short wl[128 * 128];
  const int t = threadIdx.x;
  const int lane = t & 63, w = t >> 6;

  #pragma unroll
  for (int i = 0; i < 8; ++i) {
    const int chunk = i * 256 + t;
    const int p = chunk >> 4, cseg = chunk & 15;
    const float4 wa = *(const float4*)(W + (size_t)p * 128 + cseg * 8);
    const float4 wb = *(const float4*)(W + (size_t)p * 128 + cseg * 8 + 4);
    uint4 pk;
    pk.x = pack_bf2(wa.x, wa.y); pk.y = pack_bf2(wa.z, wa.w);
    pk.z = pack_bf2(wb.x, wb.y); pk.w = pack_bf2(wb.z, wb.w);
    *(uint4*)((char*)wl + p * 256 + ((cseg * 16) ^ ((p & 7) << 4))) = pk;
  }
  __syncthreads();

  const int rowtile = blockIdx.x * 64 + w * 16;
  const int kslot = lane & 15, kgrp = lane >> 4;
  const float* Arow = A + (size_t)(rowtile + kslot) * 128;

  f32x4 acc[8];
  #pragma unroll
  for (int tt = 0; tt < 8; ++tt) acc[tt] = (f32x4){0.f, 0.f, 0.f, 0.f};

  #pragma unroll
  for (int s = 0; s < 4; ++s) {
    const int c0 = s * 32 + kgrp * 8;
    const float4 qa = *(const float4*)(Arow + c0);
    const float4 qb = *(const float4*)(Arow + c0 + 4);
    uint4 af;
    af.x = pack_bf2(qa.x, qa.y); af.y = pack_bf2(qa.z, qa.w);
    af.z = pack_bf2(qb.x, qb.y); af.w = pack_bf2(qb.z, qb.w);
    const bf16x8 Af = __builtin_bit_cast(bf16x8, af);
    const int cbyte = s * 64 + kgrp * 16;
    #pragma unroll
    for (int tt = 0; tt < 8; ++tt) {
      const int prow = tt * 16 + kslot;
      const uint4 bw = *(const uint4*)((const char*)wl + prow * 256 + (cbyte ^ ((prow & 7) << 4)));
      acc[tt] = __builtin_amdgcn_mfma_f32_16x16x32_bf16(Af, __builtin_bit_cast(bf16x8, bw), acc[tt], 0, 0, 0);
    }
  }

  #pragma unroll
  for (int tt = 0; tt < 8; ++tt) {
    const int col = tt * 16 + kslot;
    const float bb = bias[col];
    #pragma unroll
    for (int r = 0; r < 4; ++r) {
      const int row = rowtile + kgrp * 4 + r;
      Out[(size_t)row * 128 + col] = acc[tt][r] + bb;
    }
  }
}

// ---------------- binned KNN (one wave per query) + fused BN1 stats ----------------
// q = bid*4 + wave: deterministic, complete coverage, no descriptors, no early returns.
// Tier-0: TP-ball box scan (<=16 rows). cnt in [16,CAP] -> pool top-16 == global top-16
// (every non-pool point is strictly farther than the 16th). Else tier-1 at TF=0.2
// (corner-safe, proven). Else exact full scan over bp. All tiers use the exact fmaf
// distance + original-idx u64 keys -> output independent of scatter order.
__global__ __launch_bounds__(256) void k_knn(const int* __restrict__ tab,
                                             const float4* __restrict__ bp,
                                             const float* __restrict__ xyz_last,
                                             const float* __restrict__ Q,
                                             const float* __restrict__ Kp,
                                             int* __restrict__ idxo,
                                             float* __restrict__ st1) {
  __shared__ unsigned long long pool[4][CAPF];   // 4*408*8 = 13056 B
  __shared__ int sidx[4][16];
  const int t = threadIdx.x, lane = t & 63, wave = t >> 6;
  const int q = blockIdx.x * 4 + wave;           // 2048 blocks x 4 waves = 8192
  const float qx = xyz_last[q * 3];
  const float qy = xyz_last[q * 3 + 1];
  const float qz = xyz_last[q * 3 + 2];
  const int* poff = &tab[T_POFF];
  const unsigned long long below = (1ull << lane) - 1ull;

  int cnt = scan_ball(poff, bp, qx, qy, qz, TP, TP2, CAP, &pool[wave][0], lane, below);
  if (cnt >= 16 && cnt <= CAP) {
    extract_topk<3>(&pool[wave][0], cnt, lane, &sidx[wave][0], &idxo[q * 16]);
  } else {
    cnt = scan_ball(poff, bp, qx, qy, qz, TF, TF2, CAPF, &pool[wave][0], lane, below);
    if (cnt >= 16 && cnt <= CAPF) {
      extract_topk<7>(&pool[wave][0], cnt, lane, &sidx[wave][0], &idxo[q * 16]);
    } else {
      // exact full scan over all binned points (pad excluded: it < 128)
      unsigned long long key[16];
      #pragma unroll
      for (int u = 0; u < 16; ++u) key[u] = ~0ull;
      for (int it = 0; it < NPTS / 64; ++it) {
        const float4 pp = bp[it * 64 + lane];
        float dx = qx - pp.x, dy = qy - pp.y, dz = qz - pp.z;
        float dd = fmaf(dx, dx, fmaf(dy, dy, dz * dz));
        insert16(key, ((unsigned long long)__float_as_uint(dd) << 32) | (unsigned int)__float_as_int(pp.w));
      }
      unsigned long long myout = ~0ull;
      #pragma unroll 1
      for (int r = 0; r < 16; ++r) {
        unsigned long long w = key[0];
        #pragma unroll
        for (int o = 32; o; o >>= 1) {
          unsigned long long u = __shfl_xor(w, o);
          w = (u < w) ? u : w;
        }
        if (key[0] == w) {
          #pragma unroll
          for (int u = 0; u < 15; ++u) key[u] = key[u + 1];
          key[15] = ~0ull;
        }
        if (lane == r) myout = w;
      }
      if (lane < 16) {
        idxo[q * 16 + lane] = (int)(myout & 0xffffffffull);
        sidx[wave][lane] = (int)(myout & 0xffffffffull);
      }
    }
  }

  // ---- fused BN1 stats: lane owns channels 2*lane, 2*lane+1 ----
  const int c0 = lane * 2;
  const float2 qv = *(const float2*)(Q + (size_t)q * 128 + c0);
  float s0 = 0.f, s1 = 0.f, v0 = 0.f, v1 = 0.f;
  #pragma unroll 4
  for (int k = 0; k < 16; ++k) {
    const int pid = sidx[wave][k];
    const float2 kv = *(const float2*)(Kp + (size_t)pid * 128 + c0);
    const float w0 = qv.x - kv.x, w1 = qv.y - kv.y;
    s0 += w0; v0 += w0 * w0;
    s1 += w1; v1 += w1 * w1;
  }
  const int slot = (blockIdx.x & 15) * 256;
  atomicAdd(&st1[slot + c0],       s0);
  atomicAdd(&st1[slot + c0 + 1],   s1);
  atomicAdd(&st1[slot + 128 + c0], v0);
  atomicAdd(&st1[slot + 129 + c0], v1);
}

// ---------------- BN finalize ----------------
__global__ void k_bnfin(const float* __restrict__ stats, int nrep, float invM,
                        const float* __restrict__ gamma, const float* __restrict__ beta,
                        float* __restrict__ bn) {
  const int o = threadIdx.x;
  float s = 0.f, q = 0.f;
  for (int r = 0; r < nrep; ++r) { s += stats[r * 256 + o]; q += stats[r * 256 + 128 + o]; }
  float mean = s * invM;
  float var  = fmaf(-mean, mean, q * invM);
  float sc = gamma[o] * rsqrtf(var + BN_EPS);
  bn[o]       = sc;
  bn[128 + o] = fmaf(-mean, sc, beta[o]);
}

// ---------------- mid GEMM via MFMA (unchanged, proven R7-R9) ----------------
__global__ __launch_bounds__(256) void k_mid(const float* __restrict__ Q,
                                             const float* __restrict__ Kp,
                                             const int* __restrict__ idx,
                                             const float* __restrict__ Wl,
                                             const float* __restrict__ bl,
                                             const float* __restrict__ bn1,
                                             float* __restrict__ stats2,
                                             unsigned short* __restrict__ Y) {
  __shared__ union {
    unsigned short wl[128 * 128];
    struct {
      unsigned short stage[64][136];
      float red[4 * 256];
    } ep;
  } sm;

  const int t = threadIdx.x;
  const int lane = t & 63, w = t >> 6;
  const int rowbase = blockIdx.x * 64;

  #pragma unroll
  for (int i = 0; i < 8; ++i) {
    const int chunk = i * 256 + t;
    const int p = chunk >> 4, cseg = chunk & 15;
    const float4 wa = *(const float4*)(Wl + (size_t)p * 128 + cseg * 8);
    const float4 wb = *(const float4*)(Wl + (size_t)p * 128 + cseg * 8 + 4);
    uint4 pk;
    pk.x = pack_bf2(wa.x, wa.y); pk.y = pack_bf2(wa.z, wa.w);
    pk.z = pack_bf2(wb.x, wb.y); pk.w = pack_bf2(wb.z, wb.w);
    *(uint4*)((char*)sm.wl + p * 256 + ((cseg * 16) ^ ((p & 7) << 4))) = pk;
  }
  __syncthreads();

  const int n = blockIdx.x * 4 + w;
  const int kslot = lane & 15;
  const int kgrp  = lane >> 4;
  const int pid = idx[n * 16 + kslot];
  const float* Qrow = Q + (size_t)n * 128;
  const float* Krow = Kp + (size_t)pid * 128;

  f32x4 acc[8];
  #pragma unroll
  for (int tt = 0; tt < 8; ++tt) acc[tt] = (f32x4){0.f, 0.f, 0.f, 0.f};

  #pragma unroll
  for (int s = 0; s < 4; ++s) {
    const int c0 = s * 32 + kgrp * 8;
    const float4 qa = *(const float4*)(Qrow + c0);
    const float4 qb = *(const float4*)(Qrow + c0 + 4);
    const float4 ka = *(const float4*)(Krow + c0);
    const float4 kb = *(const float4*)(Krow + c0 + 4);
    const float4 sa = *(const float4*)(bn1 + c0);
    const float4 sb = *(const float4*)(bn1 + c0 + 4);
    const float4 ha = *(const float4*)(bn1 + 128 + c0);
    const float4 hb = *(const float4*)(bn1 + 128 + c0 + 4);
    float x[8];
    x[0] = fmaf(qa.x - ka.x, sa.x, ha.x);
    x[1] = fmaf(qa.y - ka.y, sa.y, ha.y);
    x[2] = fmaf(qa.z - ka.z, sa.z, ha.z);
    x[3] = fmaf(qa.w - ka.w, sa.w, ha.w);
    x[4] = fmaf(qb.x - kb.x, sb.x, hb.x);
    x[5] = fmaf(qb.y - kb.y, sb.y, hb.y);
    x[6] = fmaf(qb.z - kb.z, sb.z, hb.z);
    x[7] = fmaf(qb.w - kb.w, sb.w, hb.w);
    uint4 af;
    af.x = pack_bf2(fmaxf(x[0], SLOPE * x[0]), fmaxf(x[1], SLOPE * x[1]));
    af.y = pack_bf2(fmaxf(x[2], SLOPE * x[2]), fmaxf(x[3], SLOPE * x[3]));
    af.z = pack_bf2(fmaxf(x[4], SLOPE * x[4]), fmaxf(x[5], SLOPE * x[5]));
    af.w = pack_bf2(fmaxf(x[6], SLOPE * x[6]), fmaxf(x[7], SLOPE * x[7]));
    const bf16x8 A = __builtin_bit_cast(bf16x8, af);
    const int cbyte = s * 64 + kgrp * 16;
    #pragma unroll
    for (int tt = 0; tt < 8; ++tt) {
      const int prow = tt * 16 + kslot;
      const uint4 bw = *(const uint4*)((const char*)sm.wl + prow * 256 + (cbyte ^ ((prow & 7) << 4)));
      acc[tt] = __builtin_amdgcn_mfma_f32_16x16x32_bf16(A, __builtin_bit_cast(bf16x8, bw), acc[tt], 0, 0, 0);
    }
  }
  __syncthreads();

  #pragma unroll
  for (int tt = 0; tt < 8; ++tt) {
    const int col = tt * 16 + kslot;
    const float bb = bl[col];
    float s = 0.f, q2 = 0.f;
    #pragma unroll
    for (int r = 0; r < 4; ++r) {
      const float v = acc[tt][r] + bb;
      s += v; q2 += v * v;
      sm.ep.stage[w * 16 + kgrp * 4 + r][col] = bf1(v);
    }
    s  += __shfl_xor(s, 16);  s  += __shfl_xor(s, 32);
    q2 += __shfl_xor(q2, 16); q2 += __shfl_xor(q2, 32);
    if (kgrp == 0) {
      sm.ep.red[w * 256 + col]       = s;
      sm.ep.red[w * 256 + 128 + col] = q2;
    }
  }
  __syncthreads();

  #pragma unroll
  for (int i = 0; i < 4; ++i) {
    const int chunk = i * 256 + t;
    const int row = chunk >> 4, cc = chunk & 15;
    const uint4 v = *(const uint4*)&sm.ep.stage[row][cc * 8];
    *(uint4*)&Y[(size_t)(rowbase + row) * 128 + cc * 8] = v;
  }
  {
    const float tot = sm.ep.red[t] + sm.ep.red[256 + t] + sm.ep.red[512 + t] + sm.ep.red[768 + t];
    atomicAdd(&stats2[(blockIdx.x & 15) * 256 + t], tot);
  }
}

// ---------------- epilogue (unchanged, proven) ----------------
__global__ __launch_bounds__(128) void k_epi(const unsigned short* __restrict__ Y,
                                             const float* __restrict__ Vp,
                                             const int* __restrict__ idx,
                                             const float* __restrict__ bn2,
                                             float* __restrict__ out) {
  const int n = blockIdx.x;
  const int p = threadIdx.x;
  const float s2 = bn2[p], sh2 = bn2[128 + p];
  float z[16];
  #pragma unroll
  for (int k = 0; k < 16; ++k) {
    float yv = bf2f(Y[(size_t)(n * 16 + k) * 128 + p]);
    float v = fmaf(yv, s2, sh2);
    z[k] = (v >= 0.f) ? v : SLOPE * v;
  }
  float m = z[0];
  #pragma unroll
  for (int k = 1; k < 16; ++k) m = fmaxf(m, z[k]);
  float acc = 0.f, denom = 0.f;
  #pragma unroll
  for (int k = 0; k < 16; ++k) {
    float e = __expf(z[k] - m);
    denom += e;
    const int pid = idx[n * 16 + k];
    acc = fmaf(e, Vp[(size_t)pid * 128 + p], acc);
  }
  out[(size_t)n * 128 + p] = acc / denom;
}

extern "C" void kernel_launch(void* const* d_in, const int* in_sizes, int n_in,
                              void* d_out, int out_size, void* d_ws, size_t ws_size,
                              hipStream_t stream) {
  const float* fea_i    = (const float*)d_in[0];
  const float* fea_last = (const float*)d_in[1];
  const float* xyz_i    = (const float*)d_in[2];
  const float* xyz_last = (const float*)d_in[3];
  // d_in[4] = batch (single batch, unused)
  const float* Wq = (const float*)d_in[5];
  const float* bq = (const float*)d_in[6];
  const float* Wk = (const float*)d_in[7];
  const float* bk = (const float*)d_in[8];
  const float* Wv = (const float*)d_in[9];
  const float* bv = (const float*)d_in[10];
  const float* g1 = (const float*)d_in[11];
  const float* b1 = (const float*)d_in[12];
  const float* Wl = (const float*)d_in[13];
  const float* bl = (const float*)d_in[14];
  const float* g2 = (const float*)d_in[15];
  const float* b2 = (const float*)d_in[16];

  if (ws_size < (size_t)WS_NEED) return;

  char* ws = (char*)d_ws;
  float*  Q      = (float*)(ws + OFF_Q);
  float*  Kp     = (float*)(ws + OFF_KP);
  float*  Vp     = (float*)(ws + OFF_VP);
  int*    tab    = (int*)  (ws + OFF_TAB);
  int*    idxb   = (int*)  (ws + OFF_IDX);
  float*  st1    = (float*)(ws + OFF_STATS);            // [16*256]
  float*  st2    = st1 + 4096;                          // [16*256]
  float*  bn1    = st1 + 8192;                          // [256]
  float*  bn2    = st1 + 8448;                          // [256]
  float4* bp     = (float4*)(ws + OFF_BIG);             // 8192+64 f4, dead after knn
  unsigned short* Y = (unsigned short*)(ws + OFF_BIG);  // aliases bp (k_mid runs after knn)

  k_zero<<<33, 256, 0, stream>>>(tab, st1, bp);
  k_proj<<<dim3(128, 3), 256, 0, stream>>>(fea_i, fea_last, Wq, Wk, Wv, bq, bk, bv, Q, Kp, Vp);
  k_count<<<32, 256, 0, stream>>>(xyz_i, tab);
  k_offsets<<<1, 512, 0, stream>>>(tab);
  k_scatter<<<32, 256, 0, stream>>>(xyz_i, tab, bp);
  k_knn<<<2048, 256, 0, stream>>>(tab, bp, xyz_last, Q, Kp, idxb, st1);
  k_bnfin<<<1, 128, 0, stream>>>(st1, 16, 1.f / (float)NROWS, g1, b1, bn1);
  k_mid<<<2048, 256, 0, stream>>>(Q, Kp, idxb, Wl, bl, bn1, st2, Y);
  k_bnfin<<<1, 128, 0, stream>>>(st2, 16, 1.f / (float)NROWS, g2, b2, bn2);
  k_epi<<<8192, 128, 0, stream>>>(Y, Vp, idxb, bn2, (float*)d_out);
}

// Round 12
// 116.877 us; speedup vs baseline: 1.0826x; 1.0826x over previous
//
#include <hip/hip_runtime.h>
#include <stdint.h>

#define NPTS   8192
#define NROWS  (NPTS * 16)
#define SLOPE  0.01f
#define BN_EPS 1e-5f

// binned-KNN parameters (points binned; queries NOT binned -- one wave per query)
#define TP     0.13f     // tier-0 pool radius: interior lambda=75
#define TP2    (TP * TP)
#define LDEP   6         // tier-0 per-lane slot depth (P(lane>6 | lam=1.2) ~ 3e-5 -> tier-1)
#define LSTR   7         // padded per-lane stride in u64 (56B: breaks 32-bank alignment)
#define TF     0.2f      // tier-1 radius (corner-safe: d16 <= ~0.155, proven R6-R11)
#define TF2    0.04f
#define CAPF   408       // tier-1 cap (fits 64*LSTR=448 flat slots); fail -> exact full scan
#define EPSB   1e-5f     // conservative cell-range slop (>> fp rounding)

// ---- workspace layout (bytes) ----
#define OFF_Q      0u          // 8192x128 f32
#define OFF_KP     4194304u    // 8192x128 f32
#define OFF_VP     8388608u    // 8192x128 f32
#define OFF_STATS  12582912u   // st1[16*256] st2[16*256] bn1[256] bn2[256]
#define OFF_TAB    12845056u   // ints: pcnt[512] poff[513] pcur[512]
#define OFF_IDX    13041664u   // 131072 i32 (8192 x 16 neighbor ids)
#define OFF_BIG    13585408u   // bp[8256]f4 (dead after knn), later aliased by Y bf16 (33.5MB)
#define WS_NEED    47139840u

// TAB int offsets
#define T_PCNT 0
#define T_POFF 512
#define T_PCUR 1025

typedef __bf16 bf16x8 __attribute__((ext_vector_type(8)));
typedef float  f32x4  __attribute__((ext_vector_type(4)));

__device__ __forceinline__ unsigned int pack_bf2(float lo, float hi) {
  unsigned int a = __float_as_uint(lo);
  unsigned int b = __float_as_uint(hi);
  unsigned int ra = (a + 0x7fffu + ((a >> 16) & 1u)) >> 16;
  unsigned int rb = (b + 0x7fffu + ((b >> 16) & 1u)) & 0xffff0000u;
  return ra | rb;
}
__device__ __forceinline__ unsigned short bf1(float v) {
  unsigned int a = __float_as_uint(v);
  return (unsigned short)((a + 0x7fffu + ((a >> 16) & 1u)) >> 16);
}
__device__ __forceinline__ float bf2f(unsigned short u) {
  return __uint_as_float(((unsigned int)u) << 16);
}

__device__ __forceinline__ int cell_of(float x, float y, float z) {
  int cx = min(7, max(0, (int)(x * 8.f)));
  int cy = min(7, max(0, (int)(y * 8.f)));
  int cz = min(7, max(0, (int)(z * 8.f)));
  return (cz * 8 + cy) * 8 + cx;
}

__device__ __forceinline__ void insert16(unsigned long long* key, unsigned long long kk) {
  if (kk < key[15]) {
    #pragma unroll
    for (int u = 15; u >= 1; --u) {
      bool cm1 = kk < key[u - 1];
      bool cs  = kk < key[u];
      key[u] = cm1 ? key[u - 1] : (cs ? kk : key[u]);
    }
    key[0] = (kk < key[0]) ? kk : key[0];
  }
}

// 16 tournament rounds over per-lane sorted register slices (ascending, ~0ull = empty).
// Exact (dist, original-idx) lex order via f32-head butterfly + ballot/readlane winner
// broadcast; rare exact-dist cross-lane ties resolved by min-idx butterfly. Proven R8-R11.
template<int D>
__device__ __forceinline__ void tournament16(unsigned long long (&lst)[D], int lane,
                                             int* __restrict__ sidxq, int* __restrict__ idxoq) {
  int myidx = 0;
  #pragma unroll 1
  for (int r = 0; r < 16; ++r) {
    const float hd = __uint_as_float((unsigned int)(lst[0] >> 32));  // empty -> NaN, loses
    float wm = hd;
    #pragma unroll
    for (int o = 32; o; o >>= 1) wm = fminf(wm, __shfl_xor(wm, o));
    bool iswin = (hd == wm);
    const unsigned long long wmask = __ballot(iswin);
    unsigned int widx;
    if (__popcll(wmask) > 1) {           // exact dist tie: lex tie-break by min idx
      unsigned int mi = iswin ? (unsigned int)lst[0] : 0xffffffffu;
      #pragma unroll
      for (int o = 32; o; o >>= 1) {
        unsigned int u = (unsigned int)__shfl_xor((int)mi, o);
        mi = (u < mi) ? u : mi;
      }
      widx = mi;
      iswin = iswin && ((unsigned int)lst[0] == mi);
    } else {
      const int wl = (int)__builtin_ctzll(wmask);
      widx = (unsigned int)__builtin_amdgcn_readlane((int)(unsigned int)lst[0], wl);
    }
    #pragma unroll
    for (int u = 0; u < D - 1; ++u) lst[u] = iswin ? lst[u + 1] : lst[u];
    lst[D - 1] = iswin ? ~0ull : lst[D - 1];
    if (lane == r) myidx = (int)widx;
  }
  if (lane < 16) { idxoq[lane] = myidx; sidxq[lane] = myidx; }
}

// flat-pool slice loader + tournament (tier-1/2 path, proven R8-R11)
template<int D>
__device__ __forceinline__ void extract_topk(const unsigned long long* __restrict__ poolq, int n, int lane,
                                             int* __restrict__ sidxq, int* __restrict__ idxoq) {
  unsigned long long lst[D];
  #pragma unroll
  for (int j = 0; j < D; ++j) lst[j] = ~0ull;
  for (int j = lane; j < n; j += 64) {
    unsigned long long kk = poolq[j];
    #pragma unroll
    for (int u = D - 1; u >= 1; --u) {
      bool cm1 = kk < lst[u - 1];
      bool cs  = kk < lst[u];
      lst[u] = cm1 ? lst[u - 1] : (cs ? kk : lst[u]);
    }
    lst[0] = (kk < lst[0]) ? kk : lst[0];
  }
  tournament16<D>(lst, lane, sidxq, idxoq);
}

// ballot-append box scan (tier-1 path; proven R11). Appends exact-dd < r2 candidates
// (original idx in key) to a flat wave pool. Returns total count (past cap too).
__device__ __forceinline__ int scan_ball(const int* __restrict__ poff, const float4* __restrict__ bp,
                                         float qx, float qy, float qz, float rad, float r2, int cap,
                                         unsigned long long* __restrict__ poolw,
                                         int lane, unsigned long long below) {
  const int lx = max(0, (int)floorf((qx - rad - EPSB) * 8.f));
  const int hx = min(7, (int)floorf((qx + rad + EPSB) * 8.f));
  const int ly = max(0, (int)floorf((qy - rad - EPSB) * 8.f));
  const int hy = min(7, (int)floorf((qy + rad + EPSB) * 8.f));
  const int lz = max(0, (int)floorf((qz - rad - EPSB) * 8.f));
  const int hz = min(7, (int)floorf((qz + rad + EPSB) * 8.f));
  const int nrY = hy - ly + 1, nrows = nrY * (hz - lz + 1);
  int zi = 0;
  #pragma unroll
  for (int z2 = 1; z2 < 5; ++z2) zi += (lane >= z2 * nrY) ? 1 : 0;
  const int yi = lane - zi * nrY;
  int rs = 0, re = 0;
  if (lane < nrows) {
    const int crow = ((lz + zi) * 8 + (ly + yi)) * 8;
    rs = poff[crow + lx]; re = poff[crow + hx + 1];
  }
  int cnt = 0;
  for (int r = 0; r < nrows; ++r) {
    const int rsr = __builtin_amdgcn_readlane(rs, r);
    const int rer = __builtin_amdgcn_readlane(re, r);
    for (int base = rsr; base < rer; base += 64) {
      const int pos = base + lane;                // over-read hits sentinel pad (dd huge)
      const float4 pp = bp[pos];
      float dx = qx - pp.x, dy = qy - pp.y, dz = qz - pp.z;
      float dd = fmaf(dx, dx, fmaf(dy, dy, dz * dz));
      bool g = (pos < rer) && (dd < r2);
      unsigned long long mask = __ballot(g);
      int p2 = cnt + (int)__popcll(mask & below);
      if (g && p2 < cap)
        poolw[p2] = ((unsigned long long)__float_as_uint(dd) << 32) | (unsigned int)__float_as_int(pp.w);
      cnt += (int)__popcll(mask);
    }
  }
  return cnt;
}

// ---------------- zero counters/stats + write bp sentinel pad ----------------
__global__ __launch_bounds__(256) void k_zero(int* __restrict__ tab,
                                              float* __restrict__ stats,
                                              float4* __restrict__ bp) {
  const int T = blockIdx.x * 256 + threadIdx.x;   // 8448 threads
  if (T < 8192) stats[T] = 0.f;                   // st1[4096] + st2[4096]
  if (T < 512)  tab[T_PCNT + T] = 0;
  if (T < 64)   bp[NPTS + T] = make_float4(1e9f, 1e9f, 1e9f, __int_as_float(0));
}

// ---------------- binning: histogram (points only) ----------------
__global__ __launch_bounds__(256) void k_count(const float* __restrict__ xyz_i,
                                               int* __restrict__ tab) {
  const int t = blockIdx.x * 256 + threadIdx.x;   // 8192
  atomicAdd(&tab[T_PCNT + cell_of(xyz_i[t * 3], xyz_i[t * 3 + 1], xyz_i[t * 3 + 2])], 1);
}

// ---------------- binning: prefix sum ----------------
__global__ __launch_bounds__(512) void k_offsets(int* __restrict__ tab) {
  __shared__ int ls[512];
  const int t = threadIdx.x;
  const int v = tab[T_PCNT + t];
  ls[t] = v;
  __syncthreads();
  for (int ofs = 1; ofs < 512; ofs <<= 1) {
    int add = (t >= ofs) ? ls[t - ofs] : 0;
    __syncthreads();
    ls[t] += add;
    __syncthreads();
  }
  tab[T_POFF + t] = ls[t] - v;                    // exclusive prefix
  tab[T_PCUR + t] = ls[t] - v;
  if (t == 511) tab[T_POFF + 512] = ls[511];
}

// ---------------- binning: scatter points (original idx packed into .w) ----------------
__global__ __launch_bounds__(256) void k_scatter(const float* __restrict__ xyz_i,
                                                 int* __restrict__ tab,
                                                 float4* __restrict__ bp) {
  const int t = blockIdx.x * 256 + threadIdx.x;   // 8192
  float x = xyz_i[t * 3], y = xyz_i[t * 3 + 1], z = xyz_i[t * 3 + 2];
  int pos = atomicAdd(&tab[T_PCUR + cell_of(x, y, z)], 1);
  bp[pos] = make_float4(x, y, z, __int_as_float(t));
}

// ---------------- projections via MFMA (unchanged, proven) ----------------
__global__ __launch_bounds__(256) void k_proj(const float* __restrict__ fea_i,
                                              const float* __restrict__ fea_last,
                                              const float* __restrict__ Wq,
                                              const float* __restrict__ Wk,
                                              const float* __restrict__ Wv,
                                              const float* __restrict__ bq,
                                              const float* __restrict__ bk,
                                              const float* __restrict__ bv,
                                              float* __restrict__ Qo,
                                              float* __restrict__ Kpo,
                                              float* __restrict__ Vpo) {
  const int z = blockIdx.y;
  const float* A    = (z == 0) ? fea_last : fea_i;
  const float* W    = (z == 0) ? Wq : ((z == 1) ? Wk : Wv);
  const float* bias = (z == 0) ? bq : ((z == 1) ? bk : bv);
  float* Out        = (z == 0) ? Qo : ((z == 1) ? Kpo : Vpo);

  __shared__ unsigned short wl[128 * 128];
  const int t = threadIdx.x;
  const int lane = t & 63, w = t >> 6;

  #pragma unroll
  for (int i = 0; i < 8; ++i) {
    const int chunk = i * 256 + t;
    const int p = chunk >> 4, cseg = chunk & 15;
    const float4 wa = *(const float4*)(W + (size_t)p * 128 + cseg * 8);
    const float4 wb = *(const float4*)(W + (size_t)p * 128 + cseg * 8 + 4);
    uint4 pk;
    pk.x = pack_bf2(wa.x, wa.y); pk.y = pack_bf2(wa.z, wa.w);
    pk.z = pack_bf2(wb.x, wb.y); pk.w = pack_bf2(wb.z, wb.w);
    *(uint4*)((char*)wl + p * 256 + ((cseg * 16) ^ ((p & 7) << 4))) = pk;
  }
  __syncthreads();

  const int rowtile = blockIdx.x * 64 + w * 16;
  const int kslot = lane & 15, kgrp = lane >> 4;
  const float* Arow = A + (size_t)(rowtile + kslot) * 128;

  f32x4 acc[8];
  #pragma unroll
  for (int tt = 0; tt < 8; ++tt) acc[tt] = (f32x4){0.f, 0.f, 0.f, 0.f};

  #pragma unroll
  for (int s = 0; s < 4; ++s) {
    const int c0 = s * 32 + kgrp * 8;
    const float4 qa = *(const float4*)(Arow + c0);
    const float4 qb = *(const float4*)(Arow + c0 + 4);
    uint4 af;
    af.x = pack_bf2(qa.x, qa.y); af.y = pack_bf2(qa.z, qa.w);
    af.z = pack_bf2(qb.x, qb.y); af.w = pack_bf2(qb.z, qb.w);
    const bf16x8 Af = __builtin_bit_cast(bf16x8, af);
    const int cbyte = s * 64 + kgrp * 16;
    #pragma unroll
    for (int tt = 0; tt < 8; ++tt) {
      const int prow = tt * 16 + kslot;
      const uint4 bw = *(const uint4*)((const char*)wl + prow * 256 + (cbyte ^ ((prow & 7) << 4)));
      acc[tt] = __builtin_amdgcn_mfma_f32_16x16x32_bf16(Af, __builtin_bit_cast(bf16x8, bw), acc[tt], 0, 0, 0);
    }
  }

  #pragma unroll
  for (int tt = 0; tt < 8; ++tt) {
    const int col = tt * 16 + kslot;
    const float bb = bias[col];
    #pragma unroll
    for (int r = 0; r < 4; ++r) {
      const int row = rowtile + kgrp * 4 + r;
      Out[(size_t)row * 128 + col] = acc[tt][r] + bb;
    }
  }
}

// ---------------- binned KNN (one wave per query) + fused BN1 stats ----------------
// Tier-0 scan: NO cross-lane ops in the hot loop -- each lane appends its accepted
// candidates (exact dd < TP2) to lane-private LDS slots (stride-padded). Loads pipeline
// freely. Validity: no lane overflow (ballot) and total>=16 (butterfly); per-lane slices
// load into sorted registers -> proven tournament. Escalation (corners, rare overflows --
// both exact regardless of scatter order): tier-1 ballot scan at TF=0.2; then exact full
// scan. Stats tail: block LDS reduce (R9 pattern) -> 1 global atomic per thread.
__global__ __launch_bounds__(256) void k_knn(const int* __restrict__ tab,
                                             const float4* __restrict__ bp,
                                             const float* __restrict__ xyz_last,
                                             const float* __restrict__ Q,
                                             const float* __restrict__ Kp,
                                             int* __restrict__ idxo,
                                             float* __restrict__ st1) {
  __shared__ unsigned long long pool[4][64 * LSTR];   // 14336 B (tier-1 overlays flat: 448 >= CAPF)
  __shared__ int sidx[4][16];
  __shared__ float red[4][256];                       // 4 KB stats partials
  const int t = threadIdx.x, lane = t & 63, wave = t >> 6;
  const int q = blockIdx.x * 4 + wave;                // 2048 blocks x 4 waves = 8192
  const float qx = xyz_last[q * 3];
  const float qy = xyz_last[q * 3 + 1];
  const float qz = xyz_last[q * 3 + 2];
  const int* poff = &tab[T_POFF];
  const unsigned long long below = (1ull << lane) - 1ull;

  // ---- tier-0: lane-private append scan ----
  unsigned long long* myslots = &pool[wave][lane * LSTR];
  int cnt = 0;
  {
    const int lx = max(0, (int)floorf((qx - TP - EPSB) * 8.f));
    const int hx = min(7, (int)floorf((qx + TP + EPSB) * 8.f));
    const int ly = max(0, (int)floorf((qy - TP - EPSB) * 8.f));
    const int hy = min(7, (int)floorf((qy + TP + EPSB) * 8.f));
    const int lz = max(0, (int)floorf((qz - TP - EPSB) * 8.f));
    const int hz = min(7, (int)floorf((qz + TP + EPSB) * 8.f));
    const int nrY = hy - ly + 1, nrows = nrY * (hz - lz + 1);
    int zi = 0;
    #pragma unroll
    for (int z2 = 1; z2 < 5; ++z2) zi += (lane >= z2 * nrY) ? 1 : 0;
    const int yi = lane - zi * nrY;
    int rs = 0, re = 0;
    if (lane < nrows) {
      const int crow = ((lz + zi) * 8 + (ly + yi)) * 8;
      rs = poff[crow + lx]; re = poff[crow + hx + 1];
    }
    for (int r = 0; r < nrows; ++r) {
      const int rsr = __builtin_amdgcn_readlane(rs, r);
      const int rer = __builtin_amdgcn_readlane(re, r);
      #pragma unroll 2
      for (int base = rsr; base < rer; base += 64) {
        const int pos = base + lane;                // over-read hits sentinel pad (dd huge)
        const float4 pp = bp[pos];
        float dx = qx - pp.x, dy = qy - pp.y, dz = qz - pp.z;
        float dd = fmaf(dx, dx, fmaf(dy, dy, dz * dz));   // exact reference-ordering formula
        if ((pos < rer) && (dd < TP2)) {
          if (cnt < LDEP)
            myslots[cnt] = ((unsigned long long)__float_as_uint(dd) << 32) | (unsigned int)__float_as_int(pp.w);
          ++cnt;
        }
      }
    }
  }
  const bool anyover = __ballot(cnt > LDEP) != 0ull;
  int tot = cnt;
  #pragma unroll
  for (int o = 32; o; o >>= 1) tot += __shfl_xor(tot, o);

  if (!anyover && tot >= 16) {
    // per-lane sorted register slice from private slots, then tournament
    unsigned long long lst[LDEP];
    #pragma unroll
    for (int j = 0; j < LDEP; ++j) lst[j] = ~0ull;
    for (int j = 0; j < cnt; ++j) {
      unsigned long long kk = myslots[j];
      #pragma unroll
      for (int u = LDEP - 1; u >= 1; --u) {
        bool cm1 = kk < lst[u - 1];
        bool cs  = kk < lst[u];
        lst[u] = cm1 ? lst[u - 1] : (cs ? kk : lst[u]);
      }
      lst[0] = (kk < lst[0]) ? kk : lst[0];
    }
    tournament16<LDEP>(lst, lane, &sidx[wave][0], &idxo[q * 16]);
  } else {
    // tier-1: ballot scan at TF into flat wave pool (all candidates retained or overflow-detected)
    unsigned long long* flat = &pool[wave][0];
    int c1 = scan_ball(poff, bp, qx, qy, qz, TF, TF2, CAPF, flat, lane, below);
    if (c1 >= 16 && c1 <= CAPF) {
      extract_topk<7>(flat, c1, lane, &sidx[wave][0], &idxo[q * 16]);
    } else {
      // tier-2: exact full scan over all binned points
      unsigned long long key[16];
      #pragma unroll
      for (int u = 0; u < 16; ++u) key[u] = ~0ull;
      for (int it = 0; it < NPTS / 64; ++it) {
        const float4 pp = bp[it * 64 + lane];
        float dx = qx - pp.x, dy = qy - pp.y, dz = qz - pp.z;
        float dd = fmaf(dx, dx, fmaf(dy, dy, dz * dz));
        insert16(key, ((unsigned long long)__float_as_uint(dd) << 32) | (unsigned int)__float_as_int(pp.w));
      }
      unsigned long long myout = ~0ull;
      #pragma unroll 1
      for (int r = 0; r < 16; ++r) {
        unsigned long long w = key[0];
        #pragma unroll
        for (int o = 32; o; o >>= 1) {
          unsigned long long u = __shfl_xor(w, o);
          w = (u < w) ? u : w;
        }
        if (key[0] == w) {
          #pragma unroll
          for (int u = 0; u < 15; ++u) key[u] = key[u + 1];
          key[15] = ~0ull;
        }
        if (lane == r) myout = w;
      }
      if (lane < 16) {
        idxo[q * 16 + lane] = (int)(myout & 0xffffffffull);
        sidx[wave][lane] = (int)(myout & 0xffffffffull);
      }
    }
  }

  // ---- fused BN1 stats: lane owns channels 2*lane, 2*lane+1; block LDS reduce (R9) ----
  const int c0 = lane * 2;
  const float2 qv = *(const float2*)(Q + (size_t)q * 128 + c0);
  float s0 = 0.f, s1 = 0.f, v0 = 0.f, v1 = 0.f;
  #pragma unroll 4
  for (int k = 0; k < 16; ++k) {
    const int pid = sidx[wave][k];
    const float2 kv = *(const float2*)(Kp + (size_t)pid * 128 + c0);
    const float w0 = qv.x - kv.x, w1 = qv.y - kv.y;
    s0 += w0; v0 += w0 * w0;
    s1 += w1; v1 += w1 * w1;
  }
  red[wave][c0]       = s0;  red[wave][c0 + 1]   = s1;
  red[wave][128 + c0] = v0;  red[wave][129 + c0] = v1;
  __syncthreads();
  {
    const float totv = red[0][t & 255] + red[1][t & 255] + red[2][t & 255] + red[3][t & 255];
    atomicAdd(&st1[(blockIdx.x & 15) * 256 + (t & 255)], totv);
  }
}

// ---------------- BN finalize ----------------
__global__ void k_bnfin(const float* __restrict__ stats, int nrep, float invM,
                        const float* __restrict__ gamma, const float* __restrict__ beta,
                        float* __restrict__ bn) {
  const int o = threadIdx.x;
  float s = 0.f, q = 0.f;
  for (int r = 0; r < nrep; ++r) { s += stats[r * 256 + o]; q += stats[r * 256 + 128 + o]; }
  float mean = s * invM;
  float var  = fmaf(-mean, mean, q * invM);
  float sc = gamma[o] * rsqrtf(var + BN_EPS);
  bn[o]       = sc;
  bn[128 + o] = fmaf(-mean, sc, beta[o]);
}

// ---------------- mid GEMM via MFMA (unchanged, proven R7-R11) ----------------
__global__ __launch_bounds__(256) void k_mid(const float* __restrict__ Q,
                                             const float* __restrict__ Kp,
                                             const int* __restrict__ idx,
                                             const float* __restrict__ Wl,
                                             const float* __restrict__ bl,
                                             const float* __restrict__ bn1,
                                             float* __restrict__ stats2,
                                             unsigned short* __restrict__ Y) {
  __shared__ union {
    unsigned short wl[128 * 128];
    struct {
      unsigned short stage[64][136];
      float red[4 * 256];
    } ep;
  } sm;

  const int t = threadIdx.x;
  const int lane = t & 63, w = t >> 6;
  const int rowbase = blockIdx.x * 64;

  #pragma unroll
  for (int i = 0; i < 8; ++i) {
    const int chunk = i * 256 + t;
    const int p = chunk >> 4, cseg = chunk & 15;
    const float4 wa = *(const float4*)(Wl + (size_t)p * 128 + cseg * 8);
    const float4 wb = *(const float4*)(Wl + (size_t)p * 128 + cseg * 8 + 4);
    uint4 pk;
    pk.x = pack_bf2(wa.x, wa.y); pk.y = pack_bf2(wa.z, wa.w);
    pk.z = pack_bf2(wb.x, wb.y); pk.w = pack_bf2(wb.z, wb.w);
    *(uint4*)((char*)sm.wl + p * 256 + ((cseg * 16) ^ ((p & 7) << 4))) = pk;
  }
  __syncthreads();

  const int n = blockIdx.x * 4 + w;
  const int kslot = lane & 15;
  const int kgrp  = lane >> 4;
  const int pid = idx[n * 16 + kslot];
  const float* Qrow = Q + (size_t)n * 128;
  const float* Krow = Kp + (size_t)pid * 128;

  f32x4 acc[8];
  #pragma unroll
  for (int tt = 0; tt < 8; ++tt) acc[tt] = (f32x4){0.f, 0.f, 0.f, 0.f};

  #pragma unroll
  for (int s = 0; s < 4; ++s) {
    const int c0 = s * 32 + kgrp * 8;
    const float4 qa = *(const float4*)(Qrow + c0);
    const float4 qb = *(const float4*)(Qrow + c0 + 4);
    const float4 ka = *(const float4*)(Krow + c0);
    const float4 kb = *(const float4*)(Krow + c0 + 4);
    const float4 sa = *(const float4*)(bn1 + c0);
    const float4 sb = *(const float4*)(bn1 + c0 + 4);
    const float4 ha = *(const float4*)(bn1 + 128 + c0);
    const float4 hb = *(const float4*)(bn1 + 128 + c0 + 4);
    float x[8];
    x[0] = fmaf(qa.x - ka.x, sa.x, ha.x);
    x[1] = fmaf(qa.y - ka.y, sa.y, ha.y);
    x[2] = fmaf(qa.z - ka.z, sa.z, ha.z);
    x[3] = fmaf(qa.w - ka.w, sa.w, ha.w);
    x[4] = fmaf(qb.x - kb.x, sb.x, hb.x);
    x[5] = fmaf(qb.y - kb.y, sb.y, hb.y);
    x[6] = fmaf(qb.z - kb.z, sb.z, hb.z);
    x[7] = fmaf(qb.w - kb.w, sb.w, hb.w);
    uint4 af;
    af.x = pack_bf2(fmaxf(x[0], SLOPE * x[0]), fmaxf(x[1], SLOPE * x[1]));
    af.y = pack_bf2(fmaxf(x[2], SLOPE * x[2]), fmaxf(x[3], SLOPE * x[3]));
    af.z = pack_bf2(fmaxf(x[4], SLOPE * x[4]), fmaxf(x[5], SLOPE * x[5]));
    af.w = pack_bf2(fmaxf(x[6], SLOPE * x[6]), fmaxf(x[7], SLOPE * x[7]));
    const bf16x8 A = __builtin_bit_cast(bf16x8, af);
    const int cbyte = s * 64 + kgrp * 16;
    #pragma unroll
    for (int tt = 0; tt < 8; ++tt) {
      const int prow = tt * 16 + kslot;
      const uint4 bw = *(const uint4*)((const char*)sm.wl + prow * 256 + (cbyte ^ ((prow & 7) << 4)));
      acc[tt] = __builtin_amdgcn_mfma_f32_16x16x32_bf16(A, __builtin_bit_cast(bf16x8, bw), acc[tt], 0, 0, 0);
    }
  }
  __syncthreads();

  #pragma unroll
  for (int tt = 0; tt < 8; ++tt) {
    const int col = tt * 16 + kslot;
    const float bb = bl[col];
    float s = 0.f, q2 = 0.f;
    #pragma unroll
    for (int r = 0; r < 4; ++r) {
      const float v = acc[tt][r] + bb;
      s += v; q2 += v * v;
      sm.ep.stage[w * 16 + kgrp * 4 + r][col] = bf1(v);
    }
    s  += __shfl_xor(s, 16);  s  += __shfl_xor(s, 32);
    q2 += __shfl_xor(q2, 16); q2 += __shfl_xor(q2, 32);
    if (kgrp == 0) {
      sm.ep.red[w * 256 + col]       = s;
      sm.ep.red[w * 256 + 128 + col] = q2;
    }
  }
  __syncthreads();

  #pragma unroll
  for (int i = 0; i < 4; ++i) {
    const int chunk = i * 256 + t;
    const int row = chunk >> 4, cc = chunk & 15;
    const uint4 v = *(const uint4*)&sm.ep.stage[row][cc * 8];
    *(uint4*)&Y[(size_t)(rowbase + row) * 128 + cc * 8] = v;
  }
  {
    const float tot = sm.ep.red[t] + sm.ep.red[256 + t] + sm.ep.red[512 + t] + sm.ep.red[768 + t];
    atomicAdd(&stats2[(blockIdx.x & 15) * 256 + t], tot);
  }
}

// ---------------- epilogue (unchanged, proven) ----------------
__global__ __launch_bounds__(128) void k_epi(const unsigned short* __restrict__ Y,
                                             const float* __restrict__ Vp,
                                             const int* __restrict__ idx,
                                             const float* __restrict__ bn2,
                                             float* __restrict__ out) {
  const int n = blockIdx.x;
  const int p = threadIdx.x;
  const float s2 = bn2[p], sh2 = bn2[128 + p];
  float z[16];
  #pragma unroll
  for (int k = 0; k < 16; ++k) {
    float yv = bf2f(Y[(size_t)(n * 16 + k) * 128 + p]);
    float v = fmaf(yv, s2, sh2);
    z[k] = (v >= 0.f) ? v : SLOPE * v;
  }
  float m = z[0];
  #pragma unroll
  for (int k = 1; k < 16; ++k) m = fmaxf(m, z[k]);
  float acc = 0.f, denom = 0.f;
  #pragma unroll
  for (int k = 0; k < 16; ++k) {
    float e = __expf(z[k] - m);
    denom += e;
    const int pid = idx[n * 16 + k];
    acc = fmaf(e, Vp[(size_t)pid * 128 + p], acc);
  }
  out[(size_t)n * 128 + p] = acc / denom;
}

extern "C" void kernel_launch(void* const* d_in, const int* in_sizes, int n_in,
                              void* d_out, int out_size, void* d_ws, size_t ws_size,
                              hipStream_t stream) {
  const float* fea_i    = (const float*)d_in[0];
  const float* fea_last = (const float*)d_in[1];
  const float* xyz_i    = (const float*)d_in[2];
  const float* xyz_last = (const float*)d_in[3];
  // d_in[4] = batch (single batch, unused)
  const float* Wq = (const float*)d_in[5];
  const float* bq = (const float*)d_in[6];
  const float* Wk = (const float*)d_in[7];
  const float* bk = (const float*)d_in[8];
  const float* Wv = (const float*)d_in[9];
  const float* bv = (const float*)d_in[10];
  const float* g1 = (const float*)d_in[11];
  const float* b1 = (const float*)d_in[12];
  const float* Wl = (const float*)d_in[13];
  const float* bl = (const float*)d_in[14];
  const float* g2 = (const float*)d_in[15];
  const float* b2 = (const float*)d_in[16];

  if (ws_size < (size_t)WS_NEED) return;

  char* ws = (char*)d_ws;
  float*  Q      = (float*)(ws + OFF_Q);
  float*  Kp     = (float*)(ws + OFF_KP);
  float*  Vp     = (float*)(ws + OFF_VP);
  int*    tab    = (int*)  (ws + OFF_TAB);
  int*    idxb   = (int*)  (ws + OFF_IDX);
  float*  st1    = (float*)(ws + OFF_STATS);            // [16*256]
  float*  st2    = st1 + 4096;                          // [16*256]
  float*  bn1    = st1 + 8192;                          // [256]
  float*  bn2    = st1 + 8448;                          // [256]
  float4* bp     = (float4*)(ws + OFF_BIG);             // 8192+64 f4, dead after knn
  unsigned short* Y = (unsigned short*)(ws + OFF_BIG);  // aliases bp (k_mid runs after knn)

  k_zero<<<33, 256, 0, stream>>>(tab, st1, bp);
  k_proj<<<dim3(128, 3), 256, 0, stream>>>(fea_i, fea_last, Wq, Wk, Wv, bq, bk, bv, Q, Kp, Vp);
  k_count<<<32, 256, 0, stream>>>(xyz_i, tab);
  k_offsets<<<1, 512, 0, stream>>>(tab);
  k_scatter<<<32, 256, 0, stream>>>(xyz_i, tab, bp);
  k_knn<<<2048, 256, 0, stream>>>(tab, bp, xyz_last, Q, Kp, idxb, st1);
  k_bnfin<<<1, 128, 0, stream>>>(st1, 16, 1.f / (float)NROWS, g1, b1, bn1);
  k_mid<<<2048, 256, 0, stream>>>(Q, Kp, idxb, Wl, bl, bn1, st2, Y);
  k_bnfin<<<1, 128, 0, stream>>>(st2, 16, 1.f / (float)NROWS, g2, b2, bn2);
  k_epi<<<8192, 128, 0, stream>>>(Y, Vp, idxb, bn2, (float*)d_out);
}

// Round 13
// 104.278 us; speedup vs baseline: 1.2134x; 1.1208x over previous
//
#include <hip/hip_runtime.h>
#include <stdint.h>

#define NPTS   8192
#define NROWS  (NPTS * 16)
#define SLOPE  0.01f
#define BN_EPS 1e-5f
#define INVM   (1.f / (float)NROWS)

// binned-KNN parameters (points binned; queries NOT binned -- one wave per query)
#define TP     0.13f     // tier-0 pool radius: interior lambda=75
#define TP2    (TP * TP)
#define LDEP   6         // tier-0 per-lane slot depth (P(lane>6 | lam=1.2) ~ 3e-5 -> tier-1)
#define LSTR   7         // padded per-lane stride in u64 (56B: breaks 32-bank alignment)
#define TF     0.2f      // tier-1 radius (corner-safe: d16 <= ~0.155, proven R6-R12)
#define TF2    0.04f
#define CAPF   408       // tier-1 cap (fits 64*LSTR=448 flat slots); fail -> exact full scan
#define EPSB   1e-5f     // conservative cell-range slop (>> fp rounding)

// ---- workspace layout (bytes) ----
#define OFF_Q      0u          // 8192x128 f32
#define OFF_KP     4194304u    // 8192x128 f32
#define OFF_VP     8388608u    // 8192x128 f32
#define OFF_STATS  12582912u   // st1[16*256] st2[16*256]
#define OFF_TAB    12845056u   // ints: poff[513]
#define OFF_IDX    13041664u   // 131072 i32 (8192 x 16 neighbor ids)
#define OFF_BIG    13585408u   // bp[8256]f4 (dead after knn), later aliased by Y bf16 (33.5MB)
#define WS_NEED    47139840u

#define T_POFF 0

typedef __bf16 bf16x8 __attribute__((ext_vector_type(8)));
typedef float  f32x4  __attribute__((ext_vector_type(4)));

__device__ __forceinline__ unsigned int pack_bf2(float lo, float hi) {
  unsigned int a = __float_as_uint(lo);
  unsigned int b = __float_as_uint(hi);
  unsigned int ra = (a + 0x7fffu + ((a >> 16) & 1u)) >> 16;
  unsigned int rb = (b + 0x7fffu + ((b >> 16) & 1u)) & 0xffff0000u;
  return ra | rb;
}
__device__ __forceinline__ unsigned short bf1(float v) {
  unsigned int a = __float_as_uint(v);
  return (unsigned short)((a + 0x7fffu + ((a >> 16) & 1u)) >> 16);
}
__device__ __forceinline__ float bf2f(unsigned short u) {
  return __uint_as_float(((unsigned int)u) << 16);
}

__device__ __forceinline__ int cell_of(float x, float y, float z) {
  int cx = min(7, max(0, (int)(x * 8.f)));
  int cy = min(7, max(0, (int)(y * 8.f)));
  int cz = min(7, max(0, (int)(z * 8.f)));
  return (cz * 8 + cy) * 8 + cx;
}

__device__ __forceinline__ void insert16(unsigned long long* key, unsigned long long kk) {
  if (kk < key[15]) {
    #pragma unroll
    for (int u = 15; u >= 1; --u) {
      bool cm1 = kk < key[u - 1];
      bool cs  = kk < key[u];
      key[u] = cm1 ? key[u - 1] : (cs ? kk : key[u]);
    }
    key[0] = (kk < key[0]) ? kk : key[0];
  }
}

// 16 tournament rounds over per-lane sorted register slices (ascending, ~0ull = empty).
// Exact (dist, original-idx) lex order via f32-head butterfly + ballot/readlane winner
// broadcast; rare exact-dist cross-lane ties resolved by min-idx butterfly. Proven R8-R12.
template<int D>
__device__ __forceinline__ void tournament16(unsigned long long (&lst)[D], int lane,
                                             int* __restrict__ sidxq, int* __restrict__ idxoq) {
  int myidx = 0;
  #pragma unroll 1
  for (int r = 0; r < 16; ++r) {
    const float hd = __uint_as_float((unsigned int)(lst[0] >> 32));  // empty -> NaN, loses
    float wm = hd;
    #pragma unroll
    for (int o = 32; o; o >>= 1) wm = fminf(wm, __shfl_xor(wm, o));
    bool iswin = (hd == wm);
    const unsigned long long wmask = __ballot(iswin);
    unsigned int widx;
    if (__popcll(wmask) > 1) {           // exact dist tie: lex tie-break by min idx
      unsigned int mi = iswin ? (unsigned int)lst[0] : 0xffffffffu;
      #pragma unroll
      for (int o = 32; o; o >>= 1) {
        unsigned int u = (unsigned int)__shfl_xor((int)mi, o);
        mi = (u < mi) ? u : mi;
      }
      widx = mi;
      iswin = iswin && ((unsigned int)lst[0] == mi);
    } else {
      const int wl = (int)__builtin_ctzll(wmask);
      widx = (unsigned int)__builtin_amdgcn_readlane((int)(unsigned int)lst[0], wl);
    }
    #pragma unroll
    for (int u = 0; u < D - 1; ++u) lst[u] = iswin ? lst[u + 1] : lst[u];
    lst[D - 1] = iswin ? ~0ull : lst[D - 1];
    if (lane == r) myidx = (int)widx;
  }
  if (lane < 16) { idxoq[lane] = myidx; sidxq[lane] = myidx; }
}

// flat-pool slice loader + tournament (tier-1/2 path, proven R8-R12)
template<int D>
__device__ __forceinline__ void extract_topk(const unsigned long long* __restrict__ poolq, int n, int lane,
                                             int* __restrict__ sidxq, int* __restrict__ idxoq) {
  unsigned long long lst[D];
  #pragma unroll
  for (int j = 0; j < D; ++j) lst[j] = ~0ull;
  for (int j = lane; j < n; j += 64) {
    unsigned long long kk = poolq[j];
    #pragma unroll
    for (int u = D - 1; u >= 1; --u) {
      bool cm1 = kk < lst[u - 1];
      bool cs  = kk < lst[u];
      lst[u] = cm1 ? lst[u - 1] : (cs ? kk : lst[u]);
    }
    lst[0] = (kk < lst[0]) ? kk : lst[0];
  }
  tournament16<D>(lst, lane, sidxq, idxoq);
}

// ballot-append box scan (tier-1 path; proven R11/R12).
__device__ __forceinline__ int scan_ball(const int* __restrict__ poff, const float4* __restrict__ bp,
                                         float qx, float qy, float qz, float rad, float r2, int cap,
                                         unsigned long long* __restrict__ poolw,
                                         int lane, unsigned long long below) {
  const int lx = max(0, (int)floorf((qx - rad - EPSB) * 8.f));
  const int hx = min(7, (int)floorf((qx + rad + EPSB) * 8.f));
  const int ly = max(0, (int)floorf((qy - rad - EPSB) * 8.f));
  const int hy = min(7, (int)floorf((qy + rad + EPSB) * 8.f));
  const int lz = max(0, (int)floorf((qz - rad - EPSB) * 8.f));
  const int hz = min(7, (int)floorf((qz + rad + EPSB) * 8.f));
  const int nrY = hy - ly + 1, nrows = nrY * (hz - lz + 1);
  int zi = 0;
  #pragma unroll
  for (int z2 = 1; z2 < 5; ++z2) zi += (lane >= z2 * nrY) ? 1 : 0;
  const int yi = lane - zi * nrY;
  int rs = 0, re = 0;
  if (lane < nrows) {
    const int crow = ((lz + zi) * 8 + (ly + yi)) * 8;
    rs = poff[crow + lx]; re = poff[crow + hx + 1];
  }
  int cnt = 0;
  for (int r = 0; r < nrows; ++r) {
    const int rsr = __builtin_amdgcn_readlane(rs, r);
    const int rer = __builtin_amdgcn_readlane(re, r);
    for (int base = rsr; base < rer; base += 64) {
      const int pos = base + lane;                // over-read hits sentinel pad (dd huge)
      const float4 pp = bp[pos];
      float dx = qx - pp.x, dy = qy - pp.y, dz = qz - pp.z;
      float dd = fmaf(dx, dx, fmaf(dy, dy, dz * dz));
      bool g = (pos < rer) && (dd < r2);
      unsigned long long mask = __ballot(g);
      int p2 = cnt + (int)__popcll(mask & below);
      if (g && p2 < cap)
        poolw[p2] = ((unsigned long long)__float_as_uint(dd) << 32) | (unsigned int)__float_as_int(pp.w);
      cnt += (int)__popcll(mask);
    }
  }
  return cnt;
}

// ---------------- fused binning: zero stats + histogram + prefix + scatter + pad ----------------
// Single block of 1024 threads; phases separated by __syncthreads (exact for one block).
// Replaces k_zero + k_count + k_offsets + k_scatter. Scatter order within a cell is
// nondeterministic (LDS atomic) -- benign: downstream selection is exact over the set
// with original-index keys (proven replay-stable R11/R12).
__global__ __launch_bounds__(1024) void k_bin(const float* __restrict__ xyz_i,
                                              int* __restrict__ tab,
                                              float* __restrict__ stats,
                                              float4* __restrict__ bp) {
  __shared__ int cnt[512];
  __shared__ int scn[512];
  const int t = threadIdx.x;   // 1024
  #pragma unroll
  for (int i = 0; i < 8; ++i) stats[i * 1024 + t] = 0.f;   // st1[4096] + st2[4096]
  if (t < 512) cnt[t] = 0;
  if (t < 64)  bp[NPTS + t] = make_float4(1e9f, 1e9f, 1e9f, __int_as_float(0));
  __syncthreads();

  float xs[8], ys[8], zs[8]; int cl[8];
  #pragma unroll
  for (int i = 0; i < 8; ++i) {
    const int p = i * 1024 + t;
    xs[i] = xyz_i[p * 3]; ys[i] = xyz_i[p * 3 + 1]; zs[i] = xyz_i[p * 3 + 2];
    cl[i] = cell_of(xs[i], ys[i], zs[i]);
    atomicAdd(&cnt[cl[i]], 1);
  }
  __syncthreads();

  if (t < 512) scn[t] = cnt[t];
  __syncthreads();
  for (int ofs = 1; ofs < 512; ofs <<= 1) {
    int add = (t < 512 && t >= ofs) ? scn[t - ofs] : 0;
    __syncthreads();
    if (t < 512) scn[t] += add;
    __syncthreads();
  }
  if (t < 512) tab[T_POFF + t] = scn[t] - cnt[t];   // exclusive prefix
  if (t == 511) tab[T_POFF + 512] = scn[511];
  __syncthreads();
  if (t < 512) scn[t] -= cnt[t];                    // running cursor
  __syncthreads();

  #pragma unroll
  for (int i = 0; i < 8; ++i) {
    const int pos = atomicAdd(&scn[cl[i]], 1);
    bp[pos] = make_float4(xs[i], ys[i], zs[i], __int_as_float(i * 1024 + t));
  }
}

// ---------------- projections via MFMA (unchanged, proven) ----------------
__global__ __launch_bounds__(256) void k_proj(const float* __restrict__ fea_i,
                                              const float* __restrict__ fea_last,
                                              const float* __restrict__ Wq,
                                              const float* __restrict__ Wk,
                                              const float* __restrict__ Wv,
                                              const float* __restrict__ bq,
                                              const float* __restrict__ bk,
                                              const float* __restrict__ bv,
                                              float* __restrict__ Qo,
                                              float* __restrict__ Kpo,
                                              float* __restrict__ Vpo) {
  const int z = blockIdx.y;
  const float* A    = (z == 0) ? fea_last : fea_i;
  const float* W    = (z == 0) ? Wq : ((z == 1) ? Wk : Wv);
  const float* bias = (z == 0) ? bq : ((z == 1) ? bk : bv);
  float* Out        = (z == 0) ? Qo : ((z == 1) ? Kpo : Vpo);

  __shared__ unsigned short wl[128 * 128];
  const int t = threadIdx.x;
  const int lane = t & 63, w = t >> 6;

  #pragma unroll
  for (int i = 0; i < 8; ++i) {
    const int chunk = i * 256 + t;
    const int p = chunk >> 4, cseg = chunk & 15;
    const float4 wa = *(const float4*)(W + (size_t)p * 128 + cseg * 8);
    const float4 wb = *(const float4*)(W + (size_t)p * 128 + cseg * 8 + 4);
    uint4 pk;
    pk.x = pack_bf2(wa.x, wa.y); pk.y = pack_bf2(wa.z, wa.w);
    pk.z = pack_bf2(wb.x, wb.y); pk.w = pack_bf2(wb.z, wb.w);
    *(uint4*)((char*)wl + p * 256 + ((cseg * 16) ^ ((p & 7) << 4))) = pk;
  }
  __syncthreads();

  const int rowtile = blockIdx.x * 64 + w * 16;
  const int kslot = lane & 15, kgrp = lane >> 4;
  const float* Arow = A + (size_t)(rowtile + kslot) * 128;

  f32x4 acc[8];
  #pragma unroll
  for (int tt = 0; tt < 8; ++tt) acc[tt] = (f32x4){0.f, 0.f, 0.f, 0.f};

  #pragma unroll
  for (int s = 0; s < 4; ++s) {
    const int c0 = s * 32 + kgrp * 8;
    const float4 qa = *(const float4*)(Arow + c0);
    const float4 qb = *(const float4*)(Arow + c0 + 4);
    uint4 af;
    af.x = pack_bf2(qa.x, qa.y); af.y = pack_bf2(qa.z, qa.w);
    af.z = pack_bf2(qb.x, qb.y); af.w = pack_bf2(qb.z, qb.w);
    const bf16x8 Af = __builtin_bit_cast(bf16x8, af);
    const int cbyte = s * 64 + kgrp * 16;
    #pragma unroll
    for (int tt = 0; tt < 8; ++tt) {
      const int prow = tt * 16 + kslot;
      const uint4 bw = *(const uint4*)((const char*)wl + prow * 256 + (cbyte ^ ((prow & 7) << 4)));
      acc[tt] = __builtin_amdgcn_mfma_f32_16x16x32_bf16(Af, __builtin_bit_cast(bf16x8, bw), acc[tt], 0, 0, 0);
    }
  }

  #pragma unroll
  for (int tt = 0; tt < 8; ++tt) {
    const int col = tt * 16 + kslot;
    const float bb = bias[col];
    #pragma unroll
    for (int r = 0; r < 4; ++r) {
      const int row = rowtile + kgrp * 4 + r;
      Out[(size_t)row * 128 + col] = acc[tt][r] + bb;
    }
  }
}

// ---------------- binned KNN (one wave per query) + fused BN1 stats (unchanged R12) ----------------
__global__ __launch_bounds__(256) void k_knn(const int* __restrict__ tab,
                                             const float4* __restrict__ bp,
                                             const float* __restrict__ xyz_last,
                                             const float* __restrict__ Q,
                                             const float* __restrict__ Kp,
                                             int* __restrict__ idxo,
                                             float* __restrict__ st1) {
  __shared__ unsigned long long pool[4][64 * LSTR];   // 14336 B (tier-1 overlays flat: 448 >= CAPF)
  __shared__ int sidx[4][16];
  __shared__ float red[4][256];                       // 4 KB stats partials
  const int t = threadIdx.x, lane = t & 63, wave = t >> 6;
  const int q = blockIdx.x * 4 + wave;                // 2048 blocks x 4 waves = 8192
  const float qx = xyz_last[q * 3];
  const float qy = xyz_last[q * 3 + 1];
  const float qz = xyz_last[q * 3 + 2];
  const int* poff = &tab[T_POFF];
  const unsigned long long below = (1ull << lane) - 1ull;

  // ---- tier-0: lane-private append scan (no cross-lane ops in hot loop) ----
  unsigned long long* myslots = &pool[wave][lane * LSTR];
  int cnt = 0;
  {
    const int lx = max(0, (int)floorf((qx - TP - EPSB) * 8.f));
    const int hx = min(7, (int)floorf((qx + TP + EPSB) * 8.f));
    const int ly = max(0, (int)floorf((qy - TP - EPSB) * 8.f));
    const int hy = min(7, (int)floorf((qy + TP + EPSB) * 8.f));
    const int lz = max(0, (int)floorf((qz - TP - EPSB) * 8.f));
    const int hz = min(7, (int)floorf((qz + TP + EPSB) * 8.f));
    const int nrY = hy - ly + 1, nrows = nrY * (hz - lz + 1);
    int zi = 0;
    #pragma unroll
    for (int z2 = 1; z2 < 5; ++z2) zi += (lane >= z2 * nrY) ? 1 : 0;
    const int yi = lane - zi * nrY;
    int rs = 0, re = 0;
    if (lane < nrows) {
      const int crow = ((lz + zi) * 8 + (ly + yi)) * 8;
      rs = poff[crow + lx]; re = poff[crow + hx + 1];
    }
    for (int r = 0; r < nrows; ++r) {
      const int rsr = __builtin_amdgcn_readlane(rs, r);
      const int rer = __builtin_amdgcn_readlane(re, r);
      #pragma unroll 2
      for (int base = rsr; base < rer; base += 64) {
        const int pos = base + lane;                // over-read hits sentinel pad (dd huge)
        const float4 pp = bp[pos];
        float dx = qx - pp.x, dy = qy - pp.y, dz = qz - pp.z;
        float dd = fmaf(dx, dx, fmaf(dy, dy, dz * dz));   // exact reference-ordering formula
        if ((pos < rer) && (dd < TP2)) {
          if (cnt < LDEP)
            myslots[cnt] = ((unsigned long long)__float_as_uint(dd) << 32) | (unsigned int)__float_as_int(pp.w);
          ++cnt;
        }
      }
    }
  }
  const bool anyover = __ballot(cnt > LDEP) != 0ull;
  int tot = cnt;
  #pragma unroll
  for (int o = 32; o; o >>= 1) tot += __shfl_xor(tot, o);

  if (!anyover && tot >= 16) {
    unsigned long long lst[LDEP];
    #pragma unroll
    for (int j = 0; j < LDEP; ++j) lst[j] = ~0ull;
    for (int j = 0; j < cnt; ++j) {
      unsigned long long kk = myslots[j];
      #pragma unroll
      for (int u = LDEP - 1; u >= 1; --u) {
        bool cm1 = kk < lst[u - 1];
        bool cs  = kk < lst[u];
        lst[u] = cm1 ? lst[u - 1] : (cs ? kk : lst[u]);
      }
      lst[0] = (kk < lst[0]) ? kk : lst[0];
    }
    tournament16<LDEP>(lst, lane, &sidx[wave][0], &idxo[q * 16]);
  } else {
    unsigned long long* flat = &pool[wave][0];
    int c1 = scan_ball(poff, bp, qx, qy, qz, TF, TF2, CAPF, flat, lane, below);
    if (c1 >= 16 && c1 <= CAPF) {
      extract_topk<7>(flat, c1, lane, &sidx[wave][0], &idxo[q * 16]);
    } else {
      // tier-2: exact full scan over all binned points
      unsigned long long key[16];
      #pragma unroll
      for (int u = 0; u < 16; ++u) key[u] = ~0ull;
      for (int it = 0; it < NPTS / 64; ++it) {
        const float4 pp = bp[it * 64 + lane];
        float dx = qx - pp.x, dy = qy - pp.y, dz = qz - pp.z;
        float dd = fmaf(dx, dx, fmaf(dy, dy, dz * dz));
        insert16(key, ((unsigned long long)__float_as_uint(dd) << 32) | (unsigned int)__float_as_int(pp.w));
      }
      unsigned long long myout = ~0ull;
      #pragma unroll 1
      for (int r = 0; r < 16; ++r) {
        unsigned long long w = key[0];
        #pragma unroll
        for (int o = 32; o; o >>= 1) {
          unsigned long long u = __shfl_xor(w, o);
          w = (u < w) ? u : w;
        }
        if (key[0] == w) {
          #pragma unroll
          for (int u = 0; u < 15; ++u) key[u] = key[u + 1];
          key[15] = ~0ull;
        }
        if (lane == r) myout = w;
      }
      if (lane < 16) {
        idxo[q * 16 + lane] = (int)(myout & 0xffffffffull);
        sidx[wave][lane] = (int)(myout & 0xffffffffull);
      }
    }
  }

  // ---- fused BN1 stats: lane owns channels 2*lane, 2*lane+1; block LDS reduce ----
  const int c0 = lane * 2;
  const float2 qv = *(const float2*)(Q + (size_t)q * 128 + c0);
  float s0 = 0.f, s1 = 0.f, v0 = 0.f, v1 = 0.f;
  #pragma unroll 4
  for (int k = 0; k < 16; ++k) {
    const int pid = sidx[wave][k];
    const float2 kv = *(const float2*)(Kp + (size_t)pid * 128 + c0);
    const float w0 = qv.x - kv.x, w1 = qv.y - kv.y;
    s0 += w0; v0 += w0 * w0;
    s1 += w1; v1 += w1 * w1;
  }
  red[wave][c0]       = s0;  red[wave][c0 + 1]   = s1;
  red[wave][128 + c0] = v0;  red[wave][129 + c0] = v1;
  __syncthreads();
  {
    const float totv = red[0][t & 255] + red[1][t & 255] + red[2][t & 255] + red[3][t & 255];
    atomicAdd(&st1[(blockIdx.x & 15) * 256 + (t & 255)], totv);
  }
}

// ---------------- mid GEMM via MFMA + inline BN1 finalize ----------------
__global__ __launch_bounds__(256) void k_mid(const float* __restrict__ Q,
                                             const float* __restrict__ Kp,
                                             const int* __restrict__ idx,
                                             const float* __restrict__ Wl,
                                             const float* __restrict__ bl,
                                             const float* __restrict__ st1,
                                             const float* __restrict__ g1,
                                             const float* __restrict__ b1,
                                             float* __restrict__ stats2,
                                             unsigned short* __restrict__ Y) {
  __shared__ union {
    unsigned short wl[128 * 128];
    struct {
      unsigned short stage[64][136];
      float red[4 * 256];
    } ep;
  } sm;
  __shared__ float bn1s[256];   // [0..127]=scale [128..255]=shift

  const int t = threadIdx.x;
  const int lane = t & 63, w = t >> 6;
  const int rowbase = blockIdx.x * 64;

  #pragma unroll
  for (int i = 0; i < 8; ++i) {
    const int chunk = i * 256 + t;
    const int p = chunk >> 4, cseg = chunk & 15;
    const float4 wa = *(const float4*)(Wl + (size_t)p * 128 + cseg * 8);
    const float4 wb = *(const float4*)(Wl + (size_t)p * 128 + cseg * 8 + 4);
    uint4 pk;
    pk.x = pack_bf2(wa.x, wa.y); pk.y = pack_bf2(wa.z, wa.w);
    pk.z = pack_bf2(wb.x, wb.y); pk.w = pack_bf2(wb.z, wb.w);
    *(uint4*)((char*)sm.wl + p * 256 + ((cseg * 16) ^ ((p & 7) << 4))) = pk;
  }
  if (t < 128) {                // inline bn1 finalize (was k_bnfin): identical arithmetic
    float s = 0.f, q2 = 0.f;
    #pragma unroll
    for (int r = 0; r < 16; ++r) { s += st1[r * 256 + t]; q2 += st1[r * 256 + 128 + t]; }
    const float mean = s * INVM;
    const float var  = fmaf(-mean, mean, q2 * INVM);
    const float sc = g1[t] * rsqrtf(var + BN_EPS);
    bn1s[t]       = sc;
    bn1s[128 + t] = fmaf(-mean, sc, b1[t]);
  }
  __syncthreads();

  const int n = blockIdx.x * 4 + w;
  const int kslot = lane & 15;
  const int kgrp  = lane >> 4;
  const int pid = idx[n * 16 + kslot];
  const float* Qrow = Q + (size_t)n * 128;
  const float* Krow = Kp + (size_t)pid * 128;

  f32x4 acc[8];
  #pragma unroll
  for (int tt = 0; tt < 8; ++tt) acc[tt] = (f32x4){0.f, 0.f, 0.f, 0.f};

  #pragma unroll
  for (int s = 0; s < 4; ++s) {
    const int c0 = s * 32 + kgrp * 8;
    const float4 qa = *(const float4*)(Qrow + c0);
    const float4 qb = *(const float4*)(Qrow + c0 + 4);
    const float4 ka = *(const float4*)(Krow + c0);
    const float4 kb = *(const float4*)(Krow + c0 + 4);
    const float4 sa = *(const float4*)(bn1s + c0);
    const float4 sb = *(const float4*)(bn1s + c0 + 4);
    const float4 ha = *(const float4*)(bn1s + 128 + c0);
    const float4 hb = *(const float4*)(bn1s + 128 + c0 + 4);
    float x[8];
    x[0] = fmaf(qa.x - ka.x, sa.x, ha.x);
    x[1] = fmaf(qa.y - ka.y, sa.y, ha.y);
    x[2] = fmaf(qa.z - ka.z, sa.z, ha.z);
    x[3] = fmaf(qa.w - ka.w, sa.w, ha.w);
    x[4] = fmaf(qb.x - kb.x, sb.x, hb.x);
    x[5] = fmaf(qb.y - kb.y, sb.y, hb.y);
    x[6] = fmaf(qb.z - kb.z, sb.z, hb.z);
    x[7] = fmaf(qb.w - kb.w, sb.w, hb.w);
    uint4 af;
    af.x = pack_bf2(fmaxf(x[0], SLOPE * x[0]), fmaxf(x[1], SLOPE * x[1]));
    af.y = pack_bf2(fmaxf(x[2], SLOPE * x[2]), fmaxf(x[3], SLOPE * x[3]));
    af.z = pack_bf2(fmaxf(x[4], SLOPE * x[4]), fmaxf(x[5], SLOPE * x[5]));
    af.w = pack_bf2(fmaxf(x[6], SLOPE * x[6]), fmaxf(x[7], SLOPE * x[7]));
    const bf16x8 A = __builtin_bit_cast(bf16x8, af);
    const int cbyte = s * 64 + kgrp * 16;
    #pragma unroll
    for (int tt = 0; tt < 8; ++tt) {
      const int prow = tt * 16 + kslot;
      const uint4 bw = *(const uint4*)((const char*)sm.wl + prow * 256 + (cbyte ^ ((prow & 7) << 4)));
      acc[tt] = __builtin_amdgcn_mfma_f32_16x16x32_bf16(A, __builtin_bit_cast(bf16x8, bw), acc[tt], 0, 0, 0);
    }
  }
  __syncthreads();

  #pragma unroll
  for (int tt = 0; tt < 8; ++tt) {
    const int col = tt * 16 + kslot;
    const float bb = bl[col];
    float s = 0.f, q2 = 0.f;
    #pragma unroll
    for (int r = 0; r < 4; ++r) {
      const float v = acc[tt][r] + bb;
      s += v; q2 += v * v;
      sm.ep.stage[w * 16 + kgrp * 4 + r][col] = bf1(v);
    }
    s  += __shfl_xor(s, 16);  s  += __shfl_xor(s, 32);
    q2 += __shfl_xor(q2, 16); q2 += __shfl_xor(q2, 32);
    if (kgrp == 0) {
      sm.ep.red[w * 256 + col]       = s;
      sm.ep.red[w * 256 + 128 + col] = q2;
    }
  }
  __syncthreads();

  #pragma unroll
  for (int i = 0; i < 4; ++i) {
    const int chunk = i * 256 + t;
    const int row = chunk >> 4, cc = chunk & 15;
    const uint4 v = *(const uint4*)&sm.ep.stage[row][cc * 8];
    *(uint4*)&Y[(size_t)(rowbase + row) * 128 + cc * 8] = v;
  }
  {
    const float tot = sm.ep.red[t] + sm.ep.red[256 + t] + sm.ep.red[512 + t] + sm.ep.red[768 + t];
    atomicAdd(&stats2[(blockIdx.x & 15) * 256 + t], tot);
  }
}

// ---------------- epilogue + inline BN2 finalize ----------------
__global__ __launch_bounds__(128) void k_epi(const unsigned short* __restrict__ Y,
                                             const float* __restrict__ Vp,
                                             const int* __restrict__ idx,
                                             const float* __restrict__ st2,
                                             const float* __restrict__ g2,
                                             const float* __restrict__ b2,
                                             float* __restrict__ out) {
  const int n = blockIdx.x;
  const int p = threadIdx.x;
  float s = 0.f, q2 = 0.f;
  #pragma unroll
  for (int r = 0; r < 16; ++r) { s += st2[r * 256 + p]; q2 += st2[r * 256 + 128 + p]; }
  const float mean = s * INVM;
  const float var  = fmaf(-mean, mean, q2 * INVM);
  const float s2 = g2[p] * rsqrtf(var + BN_EPS);
  const float sh2 = fmaf(-mean, s2, b2[p]);

  float z[16];
  #pragma unroll
  for (int k = 0; k < 16; ++k) {
    float yv = bf2f(Y[(size_t)(n * 16 + k) * 128 + p]);
    float v = fmaf(yv, s2, sh2);
    z[k] = (v >= 0.f) ? v : SLOPE * v;
  }
  float m = z[0];
  #pragma unroll
  for (int k = 1; k < 16; ++k) m = fmaxf(m, z[k]);
  float acc = 0.f, denom = 0.f;
  #pragma unroll
  for (int k = 0; k < 16; ++k) {
    float e = __expf(z[k] - m);
    denom += e;
    const int pid = idx[n * 16 + k];
    acc = fmaf(e, Vp[(size_t)pid * 128 + p], acc);
  }
  out[(size_t)n * 128 + p] = acc / denom;
}

extern "C" void kernel_launch(void* const* d_in, const int* in_sizes, int n_in,
                              void* d_out, int out_size, void* d_ws, size_t ws_size,
                              hipStream_t stream) {
  const float* fea_i    = (const float*)d_in[0];
  const float* fea_last = (const float*)d_in[1];
  const float* xyz_i    = (const float*)d_in[2];
  const float* xyz_last = (const float*)d_in[3];
  // d_in[4] = batch (single batch, unused)
  const float* Wq = (const float*)d_in[5];
  const float* bq = (const float*)d_in[6];
  const float* Wk = (const float*)d_in[7];
  const float* bk = (const float*)d_in[8];
  const float* Wv = (const float*)d_in[9];
  const float* bv = (const float*)d_in[10];
  const float* g1 = (const float*)d_in[11];
  const float* b1 = (const float*)d_in[12];
  const float* Wl = (const float*)d_in[13];
  const float* bl = (const float*)d_in[14];
  const float* g2 = (const float*)d_in[15];
  const float* b2 = (const float*)d_in[16];

  if (ws_size < (size_t)WS_NEED) return;

  char* ws = (char*)d_ws;
  float*  Q      = (float*)(ws + OFF_Q);
  float*  Kp     = (float*)(ws + OFF_KP);
  float*  Vp     = (float*)(ws + OFF_VP);
  int*    tab    = (int*)  (ws + OFF_TAB);
  int*    idxb   = (int*)  (ws + OFF_IDX);
  float*  st1    = (float*)(ws + OFF_STATS);            // [16*256]
  float*  st2    = st1 + 4096;                          // [16*256]
  float4* bp     = (float4*)(ws + OFF_BIG);             // 8192+64 f4, dead after knn
  unsigned short* Y = (unsigned short*)(ws + OFF_BIG);  // aliases bp (k_mid runs after knn)

  k_bin<<<1, 1024, 0, stream>>>(xyz_i, tab, st1, bp);
  k_proj<<<dim3(128, 3), 256, 0, stream>>>(fea_i, fea_last, Wq, Wk, Wv, bq, bk, bv, Q, Kp, Vp);
  k_knn<<<2048, 256, 0, stream>>>(tab, bp, xyz_last, Q, Kp, idxb, st1);
  k_mid<<<2048, 256, 0, stream>>>(Q, Kp, idxb, Wl, bl, st1, g1, b1, st2, Y);
  k_epi<<<8192, 128, 0, stream>>>(Y, Vp, idxb, st2, g2, b2, (float*)d_out);
}